// Round 1
// baseline (287.908 us; speedup 1.0000x reference)
//
#include <hip/hip_runtime.h>
#include <hip/hip_bf16.h>

typedef __attribute__((ext_vector_type(8))) short short8v;
typedef __attribute__((ext_vector_type(4))) float f32x4;

#define T_TOK 2048
#define HDIM  2048
#define IDIM  768
#define NEXP  32
#define NGRP  8

__device__ __forceinline__ unsigned short f2b(float f){
  unsigned u = __float_as_uint(f);
  u = u + 0x7FFFu + ((u >> 16) & 1u);
  return (unsigned short)(u >> 16);
}
__device__ __forceinline__ float b2f(unsigned short s){
  return __uint_as_float(((unsigned)s) << 16);
}

// ---------------- Router: logits -> softmax -> top8 -> w_tg; also x -> bf16 ----
__global__ __launch_bounds__(256) void router_kernel(
    const float* __restrict__ x, const float* __restrict__ gw,
    const int* __restrict__ mg, float* __restrict__ wtg,
    unsigned short* __restrict__ xb)
{
  __shared__ float xs[4][2048];
  __shared__ float lg[4][32];
  int tid = threadIdx.x;
  int t0 = blockIdx.x * 4;

  // load 4 tokens (f32) into LDS, emit bf16 copy
  #pragma unroll
  for (int k = 0; k < 8; k++){
    int idx = k*256 + tid;
    int tok = idx >> 9, wi = idx & 511;
    float4 v = ((const float4*)(x + (size_t)(t0 + tok)*HDIM))[wi];
    ((float4*)xs[tok])[wi] = v;
    ushort4 b; b.x=f2b(v.x); b.y=f2b(v.y); b.z=f2b(v.z); b.w=f2b(v.w);
    ((ushort4*)(xb + (size_t)(t0+tok)*HDIM))[wi] = b;
  }
  __syncthreads();

  // logits: thread (e, ch) computes partial dot over elements {4*(ch+8k)}
  int e = tid >> 3, ch = tid & 7;
  float s0=0.f, s1=0.f, s2=0.f, s3=0.f;
  const float4* gv = (const float4*)(gw + (size_t)e*HDIM);
  #pragma unroll 4
  for (int k = 0; k < 64; k++){
    int i4 = ch + 8*k;
    float4 b  = gv[i4];
    float4 a0 = ((const float4*)xs[0])[i4];
    float4 a1 = ((const float4*)xs[1])[i4];
    float4 a2 = ((const float4*)xs[2])[i4];
    float4 a3 = ((const float4*)xs[3])[i4];
    s0 += a0.x*b.x + a0.y*b.y + a0.z*b.z + a0.w*b.w;
    s1 += a1.x*b.x + a1.y*b.y + a1.z*b.z + a1.w*b.w;
    s2 += a2.x*b.x + a2.y*b.y + a2.z*b.z + a2.w*b.w;
    s3 += a3.x*b.x + a3.y*b.y + a3.z*b.z + a3.w*b.w;
  }
  #pragma unroll
  for (int off=1; off<8; off<<=1){
    s0 += __shfl_xor(s0, off); s1 += __shfl_xor(s1, off);
    s2 += __shfl_xor(s2, off); s3 += __shfl_xor(s3, off);
  }
  if (ch == 0){ lg[0][e]=s0; lg[1][e]=s1; lg[2][e]=s2; lg[3][e]=s3; }
  __syncthreads();

  // wave wv handles token t0+wv: softmax over 32, top-8 (min-index tiebreak), group-sum
  int wv = tid >> 6, lane = tid & 63;
  float val = (lane < 32) ? lg[wv][lane] : -1e30f;
  float mx = val;
  #pragma unroll
  for (int off=16; off; off>>=1) mx = fmaxf(mx, __shfl_xor(mx, off));
  float p = (lane < 32) ? expf(val - mx) : 0.f;
  float sm = p;
  #pragma unroll
  for (int off=16; off; off>>=1) sm += __shfl_xor(sm, off);
  float v = (lane < 32) ? (p / sm) : -1.f;
  int idx = lane;
  float vals[8]; int idxs[8];
  #pragma unroll
  for (int it=0; it<8; it++){
    float bv = v; int bi = idx;
    #pragma unroll
    for (int off=32; off; off>>=1){
      float ov = __shfl_xor(bv, off); int oi = __shfl_xor(bi, off);
      if (ov > bv || (ov == bv && oi < bi)){ bv = ov; bi = oi; }
    }
    vals[it] = bv; idxs[it] = bi;
    if (lane == bi) v = -1.f;
  }
  float tot = vals[0]+vals[1]+vals[2]+vals[3]+vals[4]+vals[5]+vals[6]+vals[7];
  float racc = 0.f;
  #pragma unroll
  for (int it=0; it<8; it++){
    int grp = mg[idxs[it]];
    if (lane == grp) racc += vals[it] / tot;
  }
  if (lane < 8) wtg[(size_t)(t0+wv)*NGRP + lane] = racc;
}

// ---------------- Gather + convert expert weights f32 -> bf16 ------------------
__global__ __launch_bounds__(256) void convert_kernel(
    const float* __restrict__ src, unsigned short* __restrict__ dst,
    const int* __restrict__ de, size_t per_expert)
{
  int g = blockIdx.z;
  size_t i4 = (size_t)blockIdx.x*256 + threadIdx.x;
  const float4* s = (const float4*)(src + (size_t)de[g]*per_expert);
  float4 vv = s[i4];
  ushort4 b; b.x=f2b(vv.x); b.y=f2b(vv.y); b.z=f2b(vv.z); b.w=f2b(vv.w);
  ((ushort4*)(dst + (size_t)g*per_expert))[i4] = b;
}

// ---------------- GEMM helpers (m97-style 128x128, BK=32) ----------------------
__device__ __forceinline__ void stage128x32(const unsigned short* g,
                                            int ld, unsigned short* lds, int tid)
{
  int w = tid >> 6;
  const unsigned short* g0 = g + (size_t)(tid >> 2)*ld + (tid & 3)*8;
  const unsigned short* g1 = g0 + (size_t)64*ld;
  __builtin_amdgcn_global_load_lds((const __attribute__((address_space(1))) void*)g0,
      (__attribute__((address_space(3))) void*)(lds + w*512), 16, 0, 0);
  __builtin_amdgcn_global_load_lds((const __attribute__((address_space(1))) void*)g1,
      (__attribute__((address_space(3))) void*)(lds + 2048 + w*512), 16, 0, 0);
}

__device__ __forceinline__ void frag_mma(const unsigned short* As,
                                         const unsigned short* Bs,
                                         f32x4 acc[4][4], int lane, int wr, int wc)
{
  int fr = lane & 15, kk = (lane >> 4) * 8;
  short8v a[4], b[4];
  #pragma unroll
  for (int m=0;m<4;m++) a[m] = *(const short8v*)(As + (wr*64 + m*16 + fr)*32 + kk);
  #pragma unroll
  for (int n=0;n<4;n++) b[n] = *(const short8v*)(Bs + (wc*64 + n*16 + fr)*32 + kk);
  #pragma unroll
  for (int m=0;m<4;m++){
    #pragma unroll
    for (int n=0;n<4;n++){
      acc[m][n] = __builtin_amdgcn_mfma_f32_16x16x32_bf16(a[m], b[n], acc[m][n], 0, 0, 0);
    }
  }
}

// ---------------- GEMM1: h[g] = x (2048x2048) * gu[g]^T (1536x2048) ------------
__global__ __launch_bounds__(256, 2) void gemm1_kernel(
    const unsigned short* __restrict__ xb, const unsigned short* __restrict__ gu,
    unsigned short* __restrict__ hb)
{
  __shared__ unsigned short As[4096], Bs[4096];
  int tid = threadIdx.x, lane = tid & 63, w = tid >> 6, wr = w >> 1, wc = w & 1;
  int m0 = blockIdx.x*128, n0 = blockIdx.y*128, g = blockIdx.z;
  const unsigned short* Ab = xb + (size_t)m0*HDIM;
  const unsigned short* Bb = gu + ((size_t)g*1536 + n0)*HDIM;
  f32x4 zero = {0.f,0.f,0.f,0.f};
  f32x4 acc[4][4];
  #pragma unroll
  for (int m=0;m<4;m++){ acc[m][0]=zero; acc[m][1]=zero; acc[m][2]=zero; acc[m][3]=zero; }
  for (int k0=0; k0<HDIM; k0+=32){
    __syncthreads();
    stage128x32(Ab + k0, HDIM, As, tid);
    stage128x32(Bb + k0, HDIM, Bs, tid);
    __syncthreads();
    frag_mma(As, Bs, acc, lane, wr, wc);
  }
  int col = lane & 15, r0 = (lane >> 4) * 4;
  unsigned short* C = hb + (size_t)g*T_TOK*1536;
  #pragma unroll
  for (int m=0;m<4;m++){
    int row = m0 + wr*64 + m*16 + r0;
    #pragma unroll
    for (int n=0;n<4;n++){
      int cc = n0 + wc*64 + n*16 + col;
      #pragma unroll
      for (int j=0;j<4;j++) C[(size_t)(row + j)*1536 + cc] = f2b(acc[m][n][j]);
    }
  }
}

// ---------------- SwiGLU + weight fold: act[g,t,i] = silu(h_g)*h_u*w_tg --------
__global__ __launch_bounds__(256) void swiglu_kernel(
    const unsigned short* __restrict__ hb, const float* __restrict__ wtg,
    unsigned short* __restrict__ actb)
{
  int cid = blockIdx.x*256 + threadIdx.x;      // 0 .. 8*2048*96-1
  int g = cid / 196608;
  int rem = cid - g*196608;
  int t = rem / 96;
  int c = rem - t*96;
  const unsigned short* row = hb + ((size_t)g*T_TOK + t)*1536;
  short8v g8 = *(const short8v*)(row + c*8);
  short8v u8 = *(const short8v*)(row + 768 + c*8);
  float wv = wtg[(size_t)t*NGRP + g];
  short8v r;
  #pragma unroll
  for (int j=0;j<8;j++){
    float gf = b2f((unsigned short)g8[j]);
    float uf = b2f((unsigned short)u8[j]);
    float sg = gf / (1.f + expf(-gf));
    r[j] = (short)f2b(sg * uf * wv);
  }
  *(short8v*)(actb + ((size_t)g*T_TOK + t)*IDIM + c*8) = r;
}

// ---------------- GEMM2 split-K (z=4, 2 groups each): partials f32 -------------
__global__ __launch_bounds__(256, 2) void gemm2_kernel(
    const unsigned short* __restrict__ actb, const unsigned short* __restrict__ dnb,
    float* __restrict__ part)
{
  __shared__ unsigned short As[4096], Bs[4096];
  int tid = threadIdx.x, lane = tid & 63, w = tid >> 6, wr = w >> 1, wc = w & 1;
  int m0 = blockIdx.x*128, n0 = blockIdx.y*128, z = blockIdx.z;
  f32x4 zero = {0.f,0.f,0.f,0.f};
  f32x4 acc[4][4];
  #pragma unroll
  for (int m=0;m<4;m++){ acc[m][0]=zero; acc[m][1]=zero; acc[m][2]=zero; acc[m][3]=zero; }
  for (int gg=0; gg<2; gg++){
    int g = z*2 + gg;
    const unsigned short* Ab = actb + ((size_t)g*T_TOK + m0)*IDIM;
    const unsigned short* Bb = dnb  + ((size_t)g*HDIM  + n0)*IDIM;
    for (int k0=0; k0<IDIM; k0+=32){
      __syncthreads();
      stage128x32(Ab + k0, IDIM, As, tid);
      stage128x32(Bb + k0, IDIM, Bs, tid);
      __syncthreads();
      frag_mma(As, Bs, acc, lane, wr, wc);
    }
  }
  int col = lane & 15, r0 = (lane >> 4) * 4;
  float* C = part + (size_t)z*T_TOK*HDIM;
  #pragma unroll
  for (int m=0;m<4;m++){
    int row = m0 + wr*64 + m*16 + r0;
    #pragma unroll
    for (int n=0;n<4;n++){
      int cc = n0 + wc*64 + n*16 + col;
      #pragma unroll
      for (int j=0;j<4;j++) C[(size_t)(row + j)*HDIM + cc] = acc[m][n][j];
    }
  }
}

// ---------------- Final reduce over 4 partials ---------------------------------
__global__ __launch_bounds__(256) void reduce_kernel(
    const float* __restrict__ p, float* __restrict__ o)
{
  size_t i = ((size_t)blockIdx.x*256 + threadIdx.x)*4;
  float4 a0 = *(const float4*)(p + i);
  float4 a1 = *(const float4*)(p + 4194304 + i);
  float4 a2 = *(const float4*)(p + 8388608 + i);
  float4 a3 = *(const float4*)(p + 12582912 + i);
  float4 r;
  r.x = a0.x + a1.x + a2.x + a3.x;
  r.y = a0.y + a1.y + a2.y + a3.y;
  r.z = a0.z + a1.z + a2.z + a3.z;
  r.w = a0.w + a1.w + a2.w + a3.w;
  *(float4*)(o + i) = r;
}

extern "C" void kernel_launch(void* const* d_in, const int* in_sizes, int n_in,
                              void* d_out, int out_size, void* d_ws, size_t ws_size,
                              hipStream_t stream)
{
  (void)in_sizes; (void)n_in; (void)out_size; (void)ws_size;
  const float* x   = (const float*)d_in[0];
  const float* gw  = (const float*)d_in[1];
  const float* gup = (const float*)d_in[2];
  const float* dnp = (const float*)d_in[3];
  const int*   mg  = (const int*)d_in[4];
  const int*   de  = (const int*)d_in[5];
  float* out = (float*)d_out;
  char* ws = (char*)d_ws;

  // workspace layout (bytes):
  float*          wtg  = (float*)(ws + 0);                    //   64 KiB
  unsigned short* xb   = (unsigned short*)(ws + 65536);       //  8.0 MiB  x bf16
  unsigned short* dnb  = (unsigned short*)(ws + 8454144);     // 24.0 MiB  down bf16
  unsigned short* actb = (unsigned short*)(ws + 33619968);    // 24.0 MiB  act bf16
  unsigned short* gub  = (unsigned short*)(ws + 58785792);    // 48.0 MiB  gate_up bf16
  unsigned short* hb   = (unsigned short*)(ws + 109117440);   // 48.0 MiB  h bf16
  float*          part = (float*)(ws + 58785792);             // 64.0 MiB, aliases dead gub/hb

  router_kernel<<<512, 256, 0, stream>>>(x, gw, mg, wtg, xb);
  convert_kernel<<<dim3(3072,1,8), 256, 0, stream>>>(gup, gub, de, (size_t)1536*2048);
  convert_kernel<<<dim3(1536,1,8), 256, 0, stream>>>(dnp, dnb, de, (size_t)2048*768);
  gemm1_kernel<<<dim3(16,12,8), 256, 0, stream>>>(xb, gub, hb);
  swiglu_kernel<<<6144, 256, 0, stream>>>(hb, wtg, actb);
  gemm2_kernel<<<dim3(16,16,4), 256, 0, stream>>>(actb, dnb, part);
  reduce_kernel<<<4096, 256, 0, stream>>>(part, out);
}

// Round 2
// 287.087 us; speedup vs baseline: 1.0029x; 1.0029x over previous
//
#include <hip/hip_runtime.h>
#include <hip/hip_bf16.h>

typedef __attribute__((ext_vector_type(8))) short short8v;
typedef __attribute__((ext_vector_type(4))) float f32x4;

#define T_TOK 2048
#define HDIM  2048
#define IDIM  768
#define NEXP  32
#define NGRP  8

__device__ __forceinline__ unsigned short f2b(float f){
  unsigned u = __float_as_uint(f);
  u = u + 0x7FFFu + ((u >> 16) & 1u);
  return (unsigned short)(u >> 16);
}
__device__ __forceinline__ float b2f(unsigned short s){
  return __uint_as_float(((unsigned)s) << 16);
}

// ---------------- Router: logits -> softmax -> top8 -> w_tg; also x -> bf16 ----
__global__ __launch_bounds__(256) void router_kernel(
    const float* __restrict__ x, const float* __restrict__ gw,
    const int* __restrict__ mg, float* __restrict__ wtg,
    unsigned short* __restrict__ xb)
{
  __shared__ float xs[4][2048];
  __shared__ float lg[4][32];
  int tid = threadIdx.x;
  int t0 = blockIdx.x * 4;

  #pragma unroll
  for (int k = 0; k < 8; k++){
    int idx = k*256 + tid;
    int tok = idx >> 9, wi = idx & 511;
    float4 v = ((const float4*)(x + (size_t)(t0 + tok)*HDIM))[wi];
    ((float4*)xs[tok])[wi] = v;
    ushort4 b; b.x=f2b(v.x); b.y=f2b(v.y); b.z=f2b(v.z); b.w=f2b(v.w);
    ((ushort4*)(xb + (size_t)(t0+tok)*HDIM))[wi] = b;
  }
  __syncthreads();

  int e = tid >> 3, ch = tid & 7;
  float s0=0.f, s1=0.f, s2=0.f, s3=0.f;
  const float4* gv = (const float4*)(gw + (size_t)e*HDIM);
  #pragma unroll 4
  for (int k = 0; k < 64; k++){
    int i4 = ch + 8*k;
    float4 b  = gv[i4];
    float4 a0 = ((const float4*)xs[0])[i4];
    float4 a1 = ((const float4*)xs[1])[i4];
    float4 a2 = ((const float4*)xs[2])[i4];
    float4 a3 = ((const float4*)xs[3])[i4];
    s0 += a0.x*b.x + a0.y*b.y + a0.z*b.z + a0.w*b.w;
    s1 += a1.x*b.x + a1.y*b.y + a1.z*b.z + a1.w*b.w;
    s2 += a2.x*b.x + a2.y*b.y + a2.z*b.z + a2.w*b.w;
    s3 += a3.x*b.x + a3.y*b.y + a3.z*b.z + a3.w*b.w;
  }
  #pragma unroll
  for (int off=1; off<8; off<<=1){
    s0 += __shfl_xor(s0, off); s1 += __shfl_xor(s1, off);
    s2 += __shfl_xor(s2, off); s3 += __shfl_xor(s3, off);
  }
  if (ch == 0){ lg[0][e]=s0; lg[1][e]=s1; lg[2][e]=s2; lg[3][e]=s3; }
  __syncthreads();

  int wv = tid >> 6, lane = tid & 63;
  float val = (lane < 32) ? lg[wv][lane] : -1e30f;
  float mx = val;
  #pragma unroll
  for (int off=16; off; off>>=1) mx = fmaxf(mx, __shfl_xor(mx, off));
  float p = (lane < 32) ? expf(val - mx) : 0.f;
  float sm = p;
  #pragma unroll
  for (int off=16; off; off>>=1) sm += __shfl_xor(sm, off);
  float v = (lane < 32) ? (p / sm) : -1.f;
  int idx = lane;
  float vals[8]; int idxs[8];
  #pragma unroll
  for (int it=0; it<8; it++){
    float bv = v; int bi = idx;
    #pragma unroll
    for (int off=32; off; off>>=1){
      float ov = __shfl_xor(bv, off); int oi = __shfl_xor(bi, off);
      if (ov > bv || (ov == bv && oi < bi)){ bv = ov; bi = oi; }
    }
    vals[it] = bv; idxs[it] = bi;
    if (lane == bi) v = -1.f;
  }
  float tot = vals[0]+vals[1]+vals[2]+vals[3]+vals[4]+vals[5]+vals[6]+vals[7];
  float racc = 0.f;
  #pragma unroll
  for (int it=0; it<8; it++){
    int grp = mg[idxs[it]];
    if (lane == grp) racc += vals[it] / tot;
  }
  if (lane < 8) wtg[(size_t)(t0+wv)*NGRP + lane] = racc;
}

// ---------------- Gather + convert expert weights f32 -> bf16 ------------------
__global__ __launch_bounds__(256) void convert_kernel(
    const float* __restrict__ src, unsigned short* __restrict__ dst,
    const int* __restrict__ de, size_t per_expert)
{
  int g = blockIdx.z;
  size_t i4 = (size_t)blockIdx.x*256 + threadIdx.x;
  const float4* s = (const float4*)(src + (size_t)de[g]*per_expert);
  float4 vv = s[i4];
  ushort4 b; b.x=f2b(vv.x); b.y=f2b(vv.y); b.z=f2b(vv.z); b.w=f2b(vv.w);
  ((ushort4*)(dst + (size_t)g*per_expert))[i4] = b;
}

// ============== 256x256 / BK=64 8-phase GEMM machinery =========================
// LDS tile per operand per buffer: [256 rows][64 cols] bf16 = 32KB, st_16x32
// swizzle: byte_in_row ^= ((row&4)<<3). global_load_lds writes linearly; the
// swizzle is applied by pre-swizzling the per-lane GLOBAL source column, and
// the same XOR on every ds_read (both-sides, m173/m201 pattern).

__device__ __forceinline__ void stage_half_g(
    const unsigned short* __restrict__ gsrc, int ldElems,
    unsigned short* __restrict__ ldsHalf, int tid)
{
  int rl0 = tid >> 3;
  int cb  = (tid & 7) * 16;
  int w   = tid >> 6;
  #pragma unroll
  for (int j = 0; j < 2; j++){
    int rl  = j*64 + rl0;
    int scb = cb ^ ((rl & 4) << 3);
    const unsigned short* src = gsrc + (size_t)rl*ldElems + (scb >> 1);
    __builtin_amdgcn_global_load_lds(
        (const __attribute__((address_space(1))) void*)src,
        (__attribute__((address_space(3))) void*)(ldsHalf + j*4096 + w*512),
        16, 0, 0);
  }
}

template<int P>
__device__ __forceinline__ void read_a_frags(const unsigned short* Ab,
                                             short8v (&a)[4][2], int fr, int colOff)
{
  #pragma unroll
  for (int i=0;i<4;i++){
    const char* rb = (const char*)Ab + (size_t)(((P*4+i)*16 + fr)*128);
    a[i][0] = *(const short8v*)(rb + colOff);
    a[i][1] = *(const short8v*)(rb + 64 + colOff);
  }
}

__device__ __forceinline__ void read_b_frags(const unsigned short* Bb,
                                             short8v (&b)[2][2], int wn, int fr, int colOff)
{
  #pragma unroll
  for (int n=0;n<2;n++){
    const char* rb = (const char*)Bb + (size_t)((wn*32 + n*16 + fr)*128);
    b[n][0] = *(const short8v*)(rb + colOff);
    b[n][1] = *(const short8v*)(rb + 64 + colOff);
  }
}

template<int P>
__device__ __forceinline__ void mfma_phase(const short8v (&a)[4][2],
                                           const short8v (&b)[2][2],
                                           f32x4 (&acc)[16][2])
{
  __builtin_amdgcn_s_setprio(1);
  #pragma unroll
  for (int i=0;i<4;i++){
    #pragma unroll
    for (int n=0;n<2;n++){
      acc[P*4+i][n] = __builtin_amdgcn_mfma_f32_16x16x32_bf16(a[i][0], b[n][0], acc[P*4+i][n], 0,0,0);
      acc[P*4+i][n] = __builtin_amdgcn_mfma_f32_16x16x32_bf16(a[i][1], b[n][1], acc[P*4+i][n], 0,0,0);
    }
  }
  __builtin_amdgcn_s_setprio(0);
}

#define BARRIER() do { __builtin_amdgcn_s_barrier(); __builtin_amdgcn_sched_barrier(0); } while(0)
#define WAITV(N)  asm volatile("s_waitcnt vmcnt(" #N ")" ::: "memory")

// ---------------- GEMM1: h[g] = x (2048x2048) * gu[g]^T (1536 x 2048) ----------
__global__ __launch_bounds__(512, 2) void gemm1_kernel(
    const unsigned short* __restrict__ xb, const unsigned short* __restrict__ gu,
    unsigned short* __restrict__ hb)
{
  __shared__ unsigned short Al[2][16384];
  __shared__ unsigned short Bl[2][16384];
  int tid = threadIdx.x, lane = tid & 63, wn = tid >> 6;
  int fr = lane & 15;
  int colOff = ((lane >> 4) * 16) ^ ((lane & 4) << 3);
  int m0 = blockIdx.x * 256, n0 = blockIdx.y * 256, g = blockIdx.z;
  const unsigned short* Abase = xb + (size_t)m0 * HDIM;
  const unsigned short* Bbase = gu + ((size_t)g * 1536 + n0) * HDIM;

  f32x4 acc[16][2];
  #pragma unroll
  for (int m=0;m<16;m++){ acc[m][0] = (f32x4){0,0,0,0}; acc[m][1] = (f32x4){0,0,0,0}; }
  short8v bfrag[2][2];

  // stage unit for K-tile kt2 into buf: 0=B rows0-127, 1=B rows128-255, 2=A h0, 3=A h1
  #define STG1(buf, unit, kt2) do { \
    if ((unit)==0)      stage_half_g(Bbase + (size_t)(kt2)*64,                   HDIM, &Bl[buf][0],    tid); \
    else if ((unit)==1) stage_half_g(Bbase + (size_t)128*HDIM + (size_t)(kt2)*64,HDIM, &Bl[buf][8192], tid); \
    else if ((unit)==2) stage_half_g(Abase + (size_t)(kt2)*64,                   HDIM, &Al[buf][0],    tid); \
    else                stage_half_g(Abase + (size_t)128*HDIM + (size_t)(kt2)*64,HDIM, &Al[buf][8192], tid); \
  } while(0)

  STG1(0,0,0); STG1(0,1,0); STG1(0,2,0); STG1(0,3,0);
  WAITV(3);
  BARRIER();

  for (int kt = 0; kt < 31; ++kt){
    const unsigned short* Ab = Al[kt & 1];
    const unsigned short* Bb = Bl[kt & 1];
    int nb = (kt + 1) & 1, k2 = kt + 1;
    { short8v a[4][2]; read_a_frags<0>(Ab, a, fr, colOff);
      read_b_frags(Bb, bfrag, wn, fr, colOff);
      STG1(nb, 0, k2);
      WAITV(4); BARRIER();
      mfma_phase<0>(a, bfrag, acc);
      BARRIER(); }
    { short8v a[4][2]; read_a_frags<1>(Ab, a, fr, colOff);
      STG1(nb, 1, k2);
      WAITV(5); BARRIER();
      mfma_phase<1>(a, bfrag, acc);
      BARRIER(); }
    { short8v a[4][2]; read_a_frags<2>(Ab, a, fr, colOff);
      STG1(nb, 2, k2);
      WAITV(6); BARRIER();
      mfma_phase<2>(a, bfrag, acc);
      BARRIER(); }
    { short8v a[4][2]; read_a_frags<3>(Ab, a, fr, colOff);
      STG1(nb, 3, k2);
      WAITV(3); BARRIER();
      mfma_phase<3>(a, bfrag, acc);
      BARRIER(); }
  }
  { // tail kt = 31 (buf 1), no staging
    const unsigned short* Ab = Al[1];
    const unsigned short* Bb = Bl[1];
    { short8v a[4][2]; read_a_frags<0>(Ab, a, fr, colOff);
      read_b_frags(Bb, bfrag, wn, fr, colOff);
      WAITV(2); BARRIER();
      mfma_phase<0>(a, bfrag, acc);
      BARRIER(); }
    { short8v a[4][2]; read_a_frags<1>(Ab, a, fr, colOff);
      WAITV(1); BARRIER();
      mfma_phase<1>(a, bfrag, acc);
      BARRIER(); }
    { short8v a[4][2]; read_a_frags<2>(Ab, a, fr, colOff);
      WAITV(0); BARRIER();
      mfma_phase<2>(a, bfrag, acc);
      BARRIER(); }
    { short8v a[4][2]; read_a_frags<3>(Ab, a, fr, colOff);
      mfma_phase<3>(a, bfrag, acc); }
  }
  #undef STG1

  unsigned short* Cb = hb + (size_t)g * T_TOK * 1536;
  int r0 = (lane >> 4) * 4, c0 = n0 + wn * 32 + fr;
  #pragma unroll
  for (int m = 0; m < 16; m++){
    #pragma unroll
    for (int n = 0; n < 2; n++){
      #pragma unroll
      for (int j = 0; j < 4; j++){
        Cb[(size_t)(m0 + m*16 + r0 + j) * 1536 + (c0 + n*16)] = f2b(acc[m][n][j]);
      }
    }
  }
}

// ---------------- SwiGLU + weight fold --------------------------------------
__global__ __launch_bounds__(256) void swiglu_kernel(
    const unsigned short* __restrict__ hb, const float* __restrict__ wtg,
    unsigned short* __restrict__ actb)
{
  int cid = blockIdx.x*256 + threadIdx.x;
  int g = cid / 196608;
  int rem = cid - g*196608;
  int t = rem / 96;
  int c = rem - t*96;
  const unsigned short* row = hb + ((size_t)g*T_TOK + t)*1536;
  short8v g8 = *(const short8v*)(row + c*8);
  short8v u8 = *(const short8v*)(row + 768 + c*8);
  float wv = wtg[(size_t)t*NGRP + g];
  short8v r;
  #pragma unroll
  for (int j=0;j<8;j++){
    float gf = b2f((unsigned short)g8[j]);
    float uf = b2f((unsigned short)u8[j]);
    float sg = gf / (1.f + expf(-gf));
    r[j] = (short)f2b(sg * uf * wv);
  }
  *(short8v*)(actb + ((size_t)g*T_TOK + t)*IDIM + c*8) = r;
}

// ---------------- GEMM2 split-K (z=4, 2 groups each): partials f32 -------------
__global__ __launch_bounds__(512, 2) void gemm2_kernel(
    const unsigned short* __restrict__ actb, const unsigned short* __restrict__ dnb,
    float* __restrict__ part)
{
  __shared__ unsigned short Al[2][16384];
  __shared__ unsigned short Bl[2][16384];
  int tid = threadIdx.x, lane = tid & 63, wn = tid >> 6;
  int fr = lane & 15;
  int colOff = ((lane >> 4) * 16) ^ ((lane & 4) << 3);
  int m0 = blockIdx.x * 256, n0 = blockIdx.y * 256, z = blockIdx.z;

  f32x4 acc[16][2];
  #pragma unroll
  for (int m=0;m<16;m++){ acc[m][0] = (f32x4){0,0,0,0}; acc[m][1] = (f32x4){0,0,0,0}; }
  short8v bfrag[2][2];

  #define STG2(buf, unit, kt2) do { \
    int gi = ((kt2) >= 12) ? 1 : 0; \
    int gg = z*2 + gi; \
    int kk = ((kt2) - gi*12) * 64; \
    const unsigned short* Aseg = actb + (size_t)(gg*T_TOK + m0)*IDIM + kk; \
    const unsigned short* Bseg = dnb  + (size_t)(gg*HDIM + n0)*IDIM + kk; \
    if ((unit)==0)      stage_half_g(Bseg,                      IDIM, &Bl[buf][0],    tid); \
    else if ((unit)==1) stage_half_g(Bseg + (size_t)128*IDIM,   IDIM, &Bl[buf][8192], tid); \
    else if ((unit)==2) stage_half_g(Aseg,                      IDIM, &Al[buf][0],    tid); \
    else                stage_half_g(Aseg + (size_t)128*IDIM,   IDIM, &Al[buf][8192], tid); \
  } while(0)

  STG2(0,0,0); STG2(0,1,0); STG2(0,2,0); STG2(0,3,0);
  WAITV(3);
  BARRIER();

  for (int kt = 0; kt < 23; ++kt){
    const unsigned short* Ab = Al[kt & 1];
    const unsigned short* Bb = Bl[kt & 1];
    int nb = (kt + 1) & 1, k2 = kt + 1;
    { short8v a[4][2]; read_a_frags<0>(Ab, a, fr, colOff);
      read_b_frags(Bb, bfrag, wn, fr, colOff);
      STG2(nb, 0, k2);
      WAITV(4); BARRIER();
      mfma_phase<0>(a, bfrag, acc);
      BARRIER(); }
    { short8v a[4][2]; read_a_frags<1>(Ab, a, fr, colOff);
      STG2(nb, 1, k2);
      WAITV(5); BARRIER();
      mfma_phase<1>(a, bfrag, acc);
      BARRIER(); }
    { short8v a[4][2]; read_a_frags<2>(Ab, a, fr, colOff);
      STG2(nb, 2, k2);
      WAITV(6); BARRIER();
      mfma_phase<2>(a, bfrag, acc);
      BARRIER(); }
    { short8v a[4][2]; read_a_frags<3>(Ab, a, fr, colOff);
      STG2(nb, 3, k2);
      WAITV(3); BARRIER();
      mfma_phase<3>(a, bfrag, acc);
      BARRIER(); }
  }
  { // tail kt = 23 (buf 1)
    const unsigned short* Ab = Al[1];
    const unsigned short* Bb = Bl[1];
    { short8v a[4][2]; read_a_frags<0>(Ab, a, fr, colOff);
      read_b_frags(Bb, bfrag, wn, fr, colOff);
      WAITV(2); BARRIER();
      mfma_phase<0>(a, bfrag, acc);
      BARRIER(); }
    { short8v a[4][2]; read_a_frags<1>(Ab, a, fr, colOff);
      WAITV(1); BARRIER();
      mfma_phase<1>(a, bfrag, acc);
      BARRIER(); }
    { short8v a[4][2]; read_a_frags<2>(Ab, a, fr, colOff);
      WAITV(0); BARRIER();
      mfma_phase<2>(a, bfrag, acc);
      BARRIER(); }
    { short8v a[4][2]; read_a_frags<3>(Ab, a, fr, colOff);
      mfma_phase<3>(a, bfrag, acc); }
  }
  #undef STG2

  float* Cb = part + (size_t)z * T_TOK * HDIM;
  int r0 = (lane >> 4) * 4, c0 = n0 + wn * 32 + fr;
  #pragma unroll
  for (int m = 0; m < 16; m++){
    #pragma unroll
    for (int n = 0; n < 2; n++){
      #pragma unroll
      for (int j = 0; j < 4; j++){
        Cb[(size_t)(m0 + m*16 + r0 + j) * HDIM + (c0 + n*16)] = acc[m][n][j];
      }
    }
  }
}

// ---------------- Final reduce over 4 partials ---------------------------------
__global__ __launch_bounds__(256) void reduce_kernel(
    const float* __restrict__ p, float* __restrict__ o)
{
  size_t i = ((size_t)blockIdx.x*256 + threadIdx.x)*4;
  float4 a0 = *(const float4*)(p + i);
  float4 a1 = *(const float4*)(p + 4194304 + i);
  float4 a2 = *(const float4*)(p + 8388608 + i);
  float4 a3 = *(const float4*)(p + 12582912 + i);
  float4 r;
  r.x = a0.x + a1.x + a2.x + a3.x;
  r.y = a0.y + a1.y + a2.y + a3.y;
  r.z = a0.z + a1.z + a2.z + a3.z;
  r.w = a0.w + a1.w + a2.w + a3.w;
  *(float4*)(o + i) = r;
}

extern "C" void kernel_launch(void* const* d_in, const int* in_sizes, int n_in,
                              void* d_out, int out_size, void* d_ws, size_t ws_size,
                              hipStream_t stream)
{
  (void)in_sizes; (void)n_in; (void)out_size; (void)ws_size;
  const float* x   = (const float*)d_in[0];
  const float* gw  = (const float*)d_in[1];
  const float* gup = (const float*)d_in[2];
  const float* dnp = (const float*)d_in[3];
  const int*   mg  = (const int*)d_in[4];
  const int*   de  = (const int*)d_in[5];
  float* out = (float*)d_out;
  char* ws = (char*)d_ws;

  float*          wtg  = (float*)(ws + 0);                    //   64 KiB
  unsigned short* xb   = (unsigned short*)(ws + 65536);       //  8.0 MiB
  unsigned short* dnb  = (unsigned short*)(ws + 8454144);     // 24.0 MiB
  unsigned short* actb = (unsigned short*)(ws + 33619968);    // 24.0 MiB
  unsigned short* gub  = (unsigned short*)(ws + 58785792);    // 48.0 MiB
  unsigned short* hb   = (unsigned short*)(ws + 109117440);   // 48.0 MiB
  float*          part = (float*)(ws + 58785792);             // 64.0 MiB, aliases dead gub/hb

  router_kernel<<<512, 256, 0, stream>>>(x, gw, mg, wtg, xb);
  convert_kernel<<<dim3(3072,1,8), 256, 0, stream>>>(gup, gub, de, (size_t)1536*2048);
  convert_kernel<<<dim3(1536,1,8), 256, 0, stream>>>(dnp, dnb, de, (size_t)2048*768);
  gemm1_kernel<<<dim3(8,6,8), 512, 0, stream>>>(xb, gub, hb);
  swiglu_kernel<<<6144, 256, 0, stream>>>(hb, wtg, actb);
  gemm2_kernel<<<dim3(8,8,4), 512, 0, stream>>>(actb, dnb, part);
  reduce_kernel<<<4096, 256, 0, stream>>>(part, out);
}

// Round 3
// 269.855 us; speedup vs baseline: 1.0669x; 1.0639x over previous
//
#include <hip/hip_runtime.h>
#include <hip/hip_bf16.h>

typedef __attribute__((ext_vector_type(8))) short short8v;
typedef __attribute__((ext_vector_type(4))) float f32x4;

#define T_TOK 2048
#define HDIM  2048
#define IDIM  768
#define NEXP  32
#define NGRP  8

__device__ __forceinline__ unsigned short f2b(float f){
  unsigned u = __float_as_uint(f);
  u = u + 0x7FFFu + ((u >> 16) & 1u);
  return (unsigned short)(u >> 16);
}
__device__ __forceinline__ float b2f(unsigned short s){
  return __uint_as_float(((unsigned)s) << 16);
}

// ---------------- Router: logits -> softmax -> top8 -> w_tg; also x -> bf16 ----
__global__ __launch_bounds__(256) void router_kernel(
    const float* __restrict__ x, const float* __restrict__ gw,
    const int* __restrict__ mg, float* __restrict__ wtg,
    unsigned short* __restrict__ xb)
{
  __shared__ float xs[4][2048];
  __shared__ float lg[4][32];
  int tid = threadIdx.x;
  int t0 = blockIdx.x * 4;

  #pragma unroll
  for (int k = 0; k < 8; k++){
    int idx = k*256 + tid;
    int tok = idx >> 9, wi = idx & 511;
    float4 v = ((const float4*)(x + (size_t)(t0 + tok)*HDIM))[wi];
    ((float4*)xs[tok])[wi] = v;
    ushort4 b; b.x=f2b(v.x); b.y=f2b(v.y); b.z=f2b(v.z); b.w=f2b(v.w);
    ((ushort4*)(xb + (size_t)(t0+tok)*HDIM))[wi] = b;
  }
  __syncthreads();

  int e = tid >> 3, ch = tid & 7;
  float s0=0.f, s1=0.f, s2=0.f, s3=0.f;
  const float4* gv = (const float4*)(gw + (size_t)e*HDIM);
  #pragma unroll 4
  for (int k = 0; k < 64; k++){
    int i4 = ch + 8*k;
    float4 b  = gv[i4];
    float4 a0 = ((const float4*)xs[0])[i4];
    float4 a1 = ((const float4*)xs[1])[i4];
    float4 a2 = ((const float4*)xs[2])[i4];
    float4 a3 = ((const float4*)xs[3])[i4];
    s0 += a0.x*b.x + a0.y*b.y + a0.z*b.z + a0.w*b.w;
    s1 += a1.x*b.x + a1.y*b.y + a1.z*b.z + a1.w*b.w;
    s2 += a2.x*b.x + a2.y*b.y + a2.z*b.z + a2.w*b.w;
    s3 += a3.x*b.x + a3.y*b.y + a3.z*b.z + a3.w*b.w;
  }
  #pragma unroll
  for (int off=1; off<8; off<<=1){
    s0 += __shfl_xor(s0, off); s1 += __shfl_xor(s1, off);
    s2 += __shfl_xor(s2, off); s3 += __shfl_xor(s3, off);
  }
  if (ch == 0){ lg[0][e]=s0; lg[1][e]=s1; lg[2][e]=s2; lg[3][e]=s3; }
  __syncthreads();

  int wv = tid >> 6, lane = tid & 63;
  float val = (lane < 32) ? lg[wv][lane] : -1e30f;
  float mx = val;
  #pragma unroll
  for (int off=16; off; off>>=1) mx = fmaxf(mx, __shfl_xor(mx, off));
  float p = (lane < 32) ? expf(val - mx) : 0.f;
  float sm = p;
  #pragma unroll
  for (int off=16; off; off>>=1) sm += __shfl_xor(sm, off);
  float v = (lane < 32) ? (p / sm) : -1.f;
  int idx = lane;
  float vals[8]; int idxs[8];
  #pragma unroll
  for (int it=0; it<8; it++){
    float bv = v; int bi = idx;
    #pragma unroll
    for (int off=32; off; off>>=1){
      float ov = __shfl_xor(bv, off); int oi = __shfl_xor(bi, off);
      if (ov > bv || (ov == bv && oi < bi)){ bv = ov; bi = oi; }
    }
    vals[it] = bv; idxs[it] = bi;
    if (lane == bi) v = -1.f;
  }
  float tot = vals[0]+vals[1]+vals[2]+vals[3]+vals[4]+vals[5]+vals[6]+vals[7];
  float racc = 0.f;
  #pragma unroll
  for (int it=0; it<8; it++){
    int grp = mg[idxs[it]];
    if (lane == grp) racc += vals[it] / tot;
  }
  if (lane < 8) wtg[(size_t)(t0+wv)*NGRP + lane] = racc;
}

// ---------------- Gather + convert expert weights f32 -> bf16 ------------------
__global__ __launch_bounds__(256) void convert_kernel(
    const float* __restrict__ src, unsigned short* __restrict__ dst,
    const int* __restrict__ de, size_t per_expert)
{
  int g = blockIdx.z;
  size_t i4 = (size_t)blockIdx.x*256 + threadIdx.x;
  const float4* s = (const float4*)(src + (size_t)de[g]*per_expert);
  float4 vv = s[i4];
  ushort4 b; b.x=f2b(vv.x); b.y=f2b(vv.y); b.z=f2b(vv.z); b.w=f2b(vv.w);
  ((ushort4*)(dst + (size_t)g*per_expert))[i4] = b;
}

// ============== 256x256 / BK=64 8-phase GEMM machinery =========================
// LDS tile per operand per buffer: [256 rows][64 cols] bf16 = 32KB.
// FULL 3-bit XOR swizzle: byte_in_row ^= ((row&7)<<4)  (8 x 16B slots spread
// evenly over all 32 banks). global_load_lds writes linearly; the swizzle is
// applied by pre-swizzling the per-lane GLOBAL source column, and the same XOR
// on every ds_read (both-sides, rule 21). Second 64B chunk uses colOff^64.

__device__ __forceinline__ void stage_half_g(
    const unsigned short* __restrict__ gsrc, int ldElems,
    unsigned short* __restrict__ ldsHalf, int tid)
{
  int rl0 = tid >> 3;
  int cb  = (tid & 7) * 16;          // byte column, 8 x 16B slots per 128B row
  int w   = tid >> 6;
  #pragma unroll
  for (int j = 0; j < 2; j++){
    int rl  = j*64 + rl0;
    int scb = cb ^ ((rl & 7) << 4);  // 3-bit slot swizzle
    const unsigned short* src = gsrc + (size_t)rl*ldElems + (scb >> 1);
    __builtin_amdgcn_global_load_lds(
        (const __attribute__((address_space(1))) void*)src,
        (__attribute__((address_space(3))) void*)(ldsHalf + j*4096 + w*512),
        16, 0, 0);
  }
}

template<int P>
__device__ __forceinline__ void read_a_frags(const unsigned short* Ab,
                                             short8v (&a)[4][2], int fr, int colOff)
{
  #pragma unroll
  for (int i=0;i<4;i++){
    const char* rb = (const char*)Ab + (size_t)(((P*4+i)*16 + fr)*128);
    a[i][0] = *(const short8v*)(rb + colOff);
    a[i][1] = *(const short8v*)(rb + (colOff ^ 64));
  }
}

__device__ __forceinline__ void read_b_frags(const unsigned short* Bb,
                                             short8v (&b)[2][2], int wn, int fr, int colOff)
{
  #pragma unroll
  for (int n=0;n<2;n++){
    const char* rb = (const char*)Bb + (size_t)((wn*32 + n*16 + fr)*128);
    b[n][0] = *(const short8v*)(rb + colOff);
    b[n][1] = *(const short8v*)(rb + (colOff ^ 64));
  }
}

template<int P>
__device__ __forceinline__ void mfma_phase(const short8v (&a)[4][2],
                                           const short8v (&b)[2][2],
                                           f32x4 (&acc)[16][2])
{
  __builtin_amdgcn_s_setprio(1);
  #pragma unroll
  for (int i=0;i<4;i++){
    #pragma unroll
    for (int n=0;n<2;n++){
      acc[P*4+i][n] = __builtin_amdgcn_mfma_f32_16x16x32_bf16(a[i][0], b[n][0], acc[P*4+i][n], 0,0,0);
      acc[P*4+i][n] = __builtin_amdgcn_mfma_f32_16x16x32_bf16(a[i][1], b[n][1], acc[P*4+i][n], 0,0,0);
    }
  }
  __builtin_amdgcn_s_setprio(0);
}

#define BARRIER() do { __builtin_amdgcn_s_barrier(); __builtin_amdgcn_sched_barrier(0); } while(0)
#define WAITV(N)  asm volatile("s_waitcnt vmcnt(" #N ")" ::: "memory")

// ---------------- GEMM1: h[g] = x (2048x2048) * gu[g]^T (1536 x 2048) ----------
__global__ __launch_bounds__(512, 2) void gemm1_kernel(
    const unsigned short* __restrict__ xb, const unsigned short* __restrict__ gu,
    unsigned short* __restrict__ hb)
{
  __shared__ unsigned short Al[2][16384];
  __shared__ unsigned short Bl[2][16384];
  int tid = threadIdx.x, lane = tid & 63, wn = tid >> 6;
  int fr = lane & 15;
  int colOff = ((lane >> 4) * 16) ^ ((fr & 7) << 4);   // row&7 == fr&7
  int m0 = blockIdx.x * 256, n0 = blockIdx.y * 256, g = blockIdx.z;
  const unsigned short* Abase = xb + (size_t)m0 * HDIM;
  const unsigned short* Bbase = gu + ((size_t)g * 1536 + n0) * HDIM;

  f32x4 acc[16][2];
  #pragma unroll
  for (int m=0;m<16;m++){ acc[m][0] = (f32x4){0,0,0,0}; acc[m][1] = (f32x4){0,0,0,0}; }
  short8v bfrag[2][2];

  // stage unit for K-tile kt2 into buf: 0=B rows0-127, 1=B rows128-255, 2=A h0, 3=A h1
  #define STG1(buf, unit, kt2) do { \
    if ((unit)==0)      stage_half_g(Bbase + (size_t)(kt2)*64,                   HDIM, &Bl[buf][0],    tid); \
    else if ((unit)==1) stage_half_g(Bbase + (size_t)128*HDIM + (size_t)(kt2)*64,HDIM, &Bl[buf][8192], tid); \
    else if ((unit)==2) stage_half_g(Abase + (size_t)(kt2)*64,                   HDIM, &Al[buf][0],    tid); \
    else                stage_half_g(Abase + (size_t)128*HDIM + (size_t)(kt2)*64,HDIM, &Al[buf][8192], tid); \
  } while(0)

  STG1(0,0,0); STG1(0,1,0); STG1(0,2,0); STG1(0,3,0);
  WAITV(3);
  BARRIER();

  for (int kt = 0; kt < 31; ++kt){
    const unsigned short* Ab = Al[kt & 1];
    const unsigned short* Bb = Bl[kt & 1];
    int nb = (kt + 1) & 1, k2 = kt + 1;
    { short8v a[4][2]; read_a_frags<0>(Ab, a, fr, colOff);
      read_b_frags(Bb, bfrag, wn, fr, colOff);
      STG1(nb, 0, k2);
      WAITV(4); BARRIER();
      mfma_phase<0>(a, bfrag, acc);
      BARRIER(); }
    { short8v a[4][2]; read_a_frags<1>(Ab, a, fr, colOff);
      STG1(nb, 1, k2);
      WAITV(5); BARRIER();
      mfma_phase<1>(a, bfrag, acc);
      BARRIER(); }
    { short8v a[4][2]; read_a_frags<2>(Ab, a, fr, colOff);
      STG1(nb, 2, k2);
      WAITV(6); BARRIER();
      mfma_phase<2>(a, bfrag, acc);
      BARRIER(); }
    { short8v a[4][2]; read_a_frags<3>(Ab, a, fr, colOff);
      STG1(nb, 3, k2);
      WAITV(3); BARRIER();
      mfma_phase<3>(a, bfrag, acc);
      BARRIER(); }
  }
  { // tail kt = 31 (buf 1), no staging
    const unsigned short* Ab = Al[1];
    const unsigned short* Bb = Bl[1];
    { short8v a[4][2]; read_a_frags<0>(Ab, a, fr, colOff);
      read_b_frags(Bb, bfrag, wn, fr, colOff);
      WAITV(2); BARRIER();
      mfma_phase<0>(a, bfrag, acc);
      BARRIER(); }
    { short8v a[4][2]; read_a_frags<1>(Ab, a, fr, colOff);
      WAITV(1); BARRIER();
      mfma_phase<1>(a, bfrag, acc);
      BARRIER(); }
    { short8v a[4][2]; read_a_frags<2>(Ab, a, fr, colOff);
      WAITV(0); BARRIER();
      mfma_phase<2>(a, bfrag, acc);
      BARRIER(); }
    { short8v a[4][2]; read_a_frags<3>(Ab, a, fr, colOff);
      mfma_phase<3>(a, bfrag, acc); }
  }
  #undef STG1

  unsigned short* Cb = hb + (size_t)g * T_TOK * 1536;
  int r0 = (lane >> 4) * 4, c0 = n0 + wn * 32 + fr;
  #pragma unroll
  for (int m = 0; m < 16; m++){
    #pragma unroll
    for (int n = 0; n < 2; n++){
      #pragma unroll
      for (int j = 0; j < 4; j++){
        Cb[(size_t)(m0 + m*16 + r0 + j) * 1536 + (c0 + n*16)] = f2b(acc[m][n][j]);
      }
    }
  }
}

// ---------------- SwiGLU + weight fold --------------------------------------
__global__ __launch_bounds__(256) void swiglu_kernel(
    const unsigned short* __restrict__ hb, const float* __restrict__ wtg,
    unsigned short* __restrict__ actb)
{
  int cid = blockIdx.x*256 + threadIdx.x;
  int g = cid / 196608;
  int rem = cid - g*196608;
  int t = rem / 96;
  int c = rem - t*96;
  const unsigned short* row = hb + ((size_t)g*T_TOK + t)*1536;
  short8v g8 = *(const short8v*)(row + c*8);
  short8v u8 = *(const short8v*)(row + 768 + c*8);
  float wv = wtg[(size_t)t*NGRP + g];
  short8v r;
  #pragma unroll
  for (int j=0;j<8;j++){
    float gf = b2f((unsigned short)g8[j]);
    float uf = b2f((unsigned short)u8[j]);
    float sg = gf / (1.f + expf(-gf));
    r[j] = (short)f2b(sg * uf * wv);
  }
  *(short8v*)(actb + ((size_t)g*T_TOK + t)*IDIM + c*8) = r;
}

// ---------------- GEMM2 split-K (z=4, 2 groups each): partials f32 -------------
__global__ __launch_bounds__(512, 2) void gemm2_kernel(
    const unsigned short* __restrict__ actb, const unsigned short* __restrict__ dnb,
    float* __restrict__ part)
{
  __shared__ unsigned short Al[2][16384];
  __shared__ unsigned short Bl[2][16384];
  int tid = threadIdx.x, lane = tid & 63, wn = tid >> 6;
  int fr = lane & 15;
  int colOff = ((lane >> 4) * 16) ^ ((fr & 7) << 4);
  int m0 = blockIdx.x * 256, n0 = blockIdx.y * 256, z = blockIdx.z;

  f32x4 acc[16][2];
  #pragma unroll
  for (int m=0;m<16;m++){ acc[m][0] = (f32x4){0,0,0,0}; acc[m][1] = (f32x4){0,0,0,0}; }
  short8v bfrag[2][2];

  #define STG2(buf, unit, kt2) do { \
    int gi = ((kt2) >= 12) ? 1 : 0; \
    int gg = z*2 + gi; \
    int kk = ((kt2) - gi*12) * 64; \
    const unsigned short* Aseg = actb + (size_t)(gg*T_TOK + m0)*IDIM + kk; \
    const unsigned short* Bseg = dnb  + (size_t)(gg*HDIM + n0)*IDIM + kk; \
    if ((unit)==0)      stage_half_g(Bseg,                      IDIM, &Bl[buf][0],    tid); \
    else if ((unit)==1) stage_half_g(Bseg + (size_t)128*IDIM,   IDIM, &Bl[buf][8192], tid); \
    else if ((unit)==2) stage_half_g(Aseg,                      IDIM, &Al[buf][0],    tid); \
    else                stage_half_g(Aseg + (size_t)128*IDIM,   IDIM, &Al[buf][8192], tid); \
  } while(0)

  STG2(0,0,0); STG2(0,1,0); STG2(0,2,0); STG2(0,3,0);
  WAITV(3);
  BARRIER();

  for (int kt = 0; kt < 23; ++kt){
    const unsigned short* Ab = Al[kt & 1];
    const unsigned short* Bb = Bl[kt & 1];
    int nb = (kt + 1) & 1, k2 = kt + 1;
    { short8v a[4][2]; read_a_frags<0>(Ab, a, fr, colOff);
      read_b_frags(Bb, bfrag, wn, fr, colOff);
      STG2(nb, 0, k2);
      WAITV(4); BARRIER();
      mfma_phase<0>(a, bfrag, acc);
      BARRIER(); }
    { short8v a[4][2]; read_a_frags<1>(Ab, a, fr, colOff);
      STG2(nb, 1, k2);
      WAITV(5); BARRIER();
      mfma_phase<1>(a, bfrag, acc);
      BARRIER(); }
    { short8v a[4][2]; read_a_frags<2>(Ab, a, fr, colOff);
      STG2(nb, 2, k2);
      WAITV(6); BARRIER();
      mfma_phase<2>(a, bfrag, acc);
      BARRIER(); }
    { short8v a[4][2]; read_a_frags<3>(Ab, a, fr, colOff);
      STG2(nb, 3, k2);
      WAITV(3); BARRIER();
      mfma_phase<3>(a, bfrag, acc);
      BARRIER(); }
  }
  { // tail kt = 23 (buf 1)
    const unsigned short* Ab = Al[1];
    const unsigned short* Bb = Bl[1];
    { short8v a[4][2]; read_a_frags<0>(Ab, a, fr, colOff);
      read_b_frags(Bb, bfrag, wn, fr, colOff);
      WAITV(2); BARRIER();
      mfma_phase<0>(a, bfrag, acc);
      BARRIER(); }
    { short8v a[4][2]; read_a_frags<1>(Ab, a, fr, colOff);
      WAITV(1); BARRIER();
      mfma_phase<1>(a, bfrag, acc);
      BARRIER(); }
    { short8v a[4][2]; read_a_frags<2>(Ab, a, fr, colOff);
      WAITV(0); BARRIER();
      mfma_phase<2>(a, bfrag, acc);
      BARRIER(); }
    { short8v a[4][2]; read_a_frags<3>(Ab, a, fr, colOff);
      mfma_phase<3>(a, bfrag, acc); }
  }
  #undef STG2

  float* Cb = part + (size_t)z * T_TOK * HDIM;
  int r0 = (lane >> 4) * 4, c0 = n0 + wn * 32 + fr;
  #pragma unroll
  for (int m = 0; m < 16; m++){
    #pragma unroll
    for (int n = 0; n < 2; n++){
      #pragma unroll
      for (int j = 0; j < 4; j++){
        Cb[(size_t)(m0 + m*16 + r0 + j) * HDIM + (c0 + n*16)] = acc[m][n][j];
      }
    }
  }
}

// ---------------- Final reduce over 4 partials ---------------------------------
__global__ __launch_bounds__(256) void reduce_kernel(
    const float* __restrict__ p, float* __restrict__ o)
{
  size_t i = ((size_t)blockIdx.x*256 + threadIdx.x)*4;
  float4 a0 = *(const float4*)(p + i);
  float4 a1 = *(const float4*)(p + 4194304 + i);
  float4 a2 = *(const float4*)(p + 8388608 + i);
  float4 a3 = *(const float4*)(p + 12582912 + i);
  float4 r;
  r.x = a0.x + a1.x + a2.x + a3.x;
  r.y = a0.y + a1.y + a2.y + a3.y;
  r.z = a0.z + a1.z + a2.z + a3.z;
  r.w = a0.w + a1.w + a2.w + a3.w;
  *(float4*)(o + i) = r;
}

extern "C" void kernel_launch(void* const* d_in, const int* in_sizes, int n_in,
                              void* d_out, int out_size, void* d_ws, size_t ws_size,
                              hipStream_t stream)
{
  (void)in_sizes; (void)n_in; (void)out_size; (void)ws_size;
  const float* x   = (const float*)d_in[0];
  const float* gw  = (const float*)d_in[1];
  const float* gup = (const float*)d_in[2];
  const float* dnp = (const float*)d_in[3];
  const int*   mg  = (const int*)d_in[4];
  const int*   de  = (const int*)d_in[5];
  float* out = (float*)d_out;
  char* ws = (char*)d_ws;

  float*          wtg  = (float*)(ws + 0);                    //   64 KiB
  unsigned short* xb   = (unsigned short*)(ws + 65536);       //  8.0 MiB
  unsigned short* dnb  = (unsigned short*)(ws + 8454144);     // 24.0 MiB
  unsigned short* actb = (unsigned short*)(ws + 33619968);    // 24.0 MiB
  unsigned short* gub  = (unsigned short*)(ws + 58785792);    // 48.0 MiB
  unsigned short* hb   = (unsigned short*)(ws + 109117440);   // 48.0 MiB
  float*          part = (float*)(ws + 58785792);             // 64.0 MiB, aliases dead gub/hb

  router_kernel<<<512, 256, 0, stream>>>(x, gw, mg, wtg, xb);
  convert_kernel<<<dim3(3072,1,8), 256, 0, stream>>>(gup, gub, de, (size_t)1536*2048);
  convert_kernel<<<dim3(1536,1,8), 256, 0, stream>>>(dnp, dnb, de, (size_t)2048*768);
  gemm1_kernel<<<dim3(8,6,8), 512, 0, stream>>>(xb, gub, hb);
  swiglu_kernel<<<6144, 256, 0, stream>>>(hb, wtg, actb);
  gemm2_kernel<<<dim3(8,8,4), 512, 0, stream>>>(actb, dnb, part);
  reduce_kernel<<<4096, 256, 0, stream>>>(part, out);
}

// Round 4
// 261.671 us; speedup vs baseline: 1.1003x; 1.0313x over previous
//
#include <hip/hip_runtime.h>
#include <hip/hip_bf16.h>

typedef __attribute__((ext_vector_type(8))) short short8v;
typedef __attribute__((ext_vector_type(4))) float f32x4;

#define T_TOK 2048
#define HDIM  2048
#define IDIM  768
#define NGRP  8

__device__ __forceinline__ unsigned short f2b(float f){
  unsigned u = __float_as_uint(f);
  u = u + 0x7FFFu + ((u >> 16) & 1u);
  return (unsigned short)(u >> 16);
}
__device__ __forceinline__ float b2f(unsigned short s){
  return __uint_as_float(((unsigned)s) << 16);
}

// ---------------- Router: logits -> softmax -> top8 -> w_tg; also x -> bf16 ----
__global__ __launch_bounds__(256) void router_kernel(
    const float* __restrict__ x, const float* __restrict__ gw,
    const int* __restrict__ mg, float* __restrict__ wtg,
    unsigned short* __restrict__ xb)
{
  __shared__ float xs[4][2048];
  __shared__ float lg[4][32];
  int tid = threadIdx.x;
  int t0 = blockIdx.x * 4;

  #pragma unroll
  for (int k = 0; k < 8; k++){
    int idx = k*256 + tid;
    int tok = idx >> 9, wi = idx & 511;
    float4 v = ((const float4*)(x + (size_t)(t0 + tok)*HDIM))[wi];
    ((float4*)xs[tok])[wi] = v;
    ushort4 b; b.x=f2b(v.x); b.y=f2b(v.y); b.z=f2b(v.z); b.w=f2b(v.w);
    ((ushort4*)(xb + (size_t)(t0+tok)*HDIM))[wi] = b;
  }
  __syncthreads();

  int e = tid >> 3, ch = tid & 7;
  float s0=0.f, s1=0.f, s2=0.f, s3=0.f;
  const float4* gv = (const float4*)(gw + (size_t)e*HDIM);
  #pragma unroll 4
  for (int k = 0; k < 64; k++){
    int i4 = ch + 8*k;
    float4 b  = gv[i4];
    float4 a0 = ((const float4*)xs[0])[i4];
    float4 a1 = ((const float4*)xs[1])[i4];
    float4 a2 = ((const float4*)xs[2])[i4];
    float4 a3 = ((const float4*)xs[3])[i4];
    s0 += a0.x*b.x + a0.y*b.y + a0.z*b.z + a0.w*b.w;
    s1 += a1.x*b.x + a1.y*b.y + a1.z*b.z + a1.w*b.w;
    s2 += a2.x*b.x + a2.y*b.y + a2.z*b.z + a2.w*b.w;
    s3 += a3.x*b.x + a3.y*b.y + a3.z*b.z + a3.w*b.w;
  }
  #pragma unroll
  for (int off=1; off<8; off<<=1){
    s0 += __shfl_xor(s0, off); s1 += __shfl_xor(s1, off);
    s2 += __shfl_xor(s2, off); s3 += __shfl_xor(s3, off);
  }
  if (ch == 0){ lg[0][e]=s0; lg[1][e]=s1; lg[2][e]=s2; lg[3][e]=s3; }
  __syncthreads();

  int wv = tid >> 6, lane = tid & 63;
  float val = (lane < 32) ? lg[wv][lane] : -1e30f;
  float mx = val;
  #pragma unroll
  for (int off=16; off; off>>=1) mx = fmaxf(mx, __shfl_xor(mx, off));
  float p = (lane < 32) ? expf(val - mx) : 0.f;
  float sm = p;
  #pragma unroll
  for (int off=16; off; off>>=1) sm += __shfl_xor(sm, off);
  float v = (lane < 32) ? (p / sm) : -1.f;
  int idx = lane;
  float vals[8]; int idxs[8];
  #pragma unroll
  for (int it=0; it<8; it++){
    float bv = v; int bi = idx;
    #pragma unroll
    for (int off=32; off; off>>=1){
      float ov = __shfl_xor(bv, off); int oi = __shfl_xor(bi, off);
      if (ov > bv || (ov == bv && oi < bi)){ bv = ov; bi = oi; }
    }
    vals[it] = bv; idxs[it] = bi;
    if (lane == bi) v = -1.f;
  }
  float tot = vals[0]+vals[1]+vals[2]+vals[3]+vals[4]+vals[5]+vals[6]+vals[7];
  float racc = 0.f;
  #pragma unroll
  for (int it=0; it<8; it++){
    int grp = mg[idxs[it]];
    if (lane == grp) racc += vals[it] / tot;
  }
  if (lane < 8) wtg[(size_t)(t0+wv)*NGRP + lane] = racc;
}

// ------- Convert gate_up with gate/up 16-col interleave (for fused swiglu) -----
// out row j (0..1535): q=j>>5, r=j&31; src_row = r<16 ? q*16+r : 768+q*16+(r-16)
__global__ __launch_bounds__(256) void convert_gu_kernel(
    const float* __restrict__ src, unsigned short* __restrict__ dst,
    const int* __restrict__ de)
{
  int g = blockIdx.z;
  int i4 = blockIdx.x*256 + threadIdx.x;   // 0 .. 786431
  int j  = i4 >> 9;
  int c4 = i4 & 511;
  int q = j >> 5, r = j & 31;
  int srow = (r < 16) ? (q*16 + r) : (768 + q*16 + (r - 16));
  const float4* s = (const float4*)(src + ((size_t)de[g]*1536 + srow)*HDIM);
  float4 vv = s[c4];
  ushort4 b; b.x=f2b(vv.x); b.y=f2b(vv.y); b.z=f2b(vv.z); b.w=f2b(vv.w);
  ((ushort4*)(dst + ((size_t)g*1536 + j)*HDIM))[c4] = b;
}

__global__ __launch_bounds__(256) void convert_dn_kernel(
    const float* __restrict__ src, unsigned short* __restrict__ dst,
    const int* __restrict__ de)
{
  int g = blockIdx.z;
  size_t i4 = (size_t)blockIdx.x*256 + threadIdx.x;
  const float4* s = (const float4*)(src + (size_t)de[g]*1572864);
  float4 vv = s[i4];
  ushort4 b; b.x=f2b(vv.x); b.y=f2b(vv.y); b.z=f2b(vv.z); b.w=f2b(vv.w);
  ((ushort4*)(dst + (size_t)g*1572864))[i4] = b;
}

// ============== 256x256 / BK=64 GEMM, full-tile prefetch, 2M x 4N waves ========
// LDS [256][64] bf16 per operand per buffer, 3-bit XOR swizzle
// byte_in_row ^= ((row&7)<<4); applied on pre-swizzled global source AND reads.

__device__ __forceinline__ void stage_half_g(
    const unsigned short* __restrict__ gsrc, int ldElems,
    unsigned short* __restrict__ ldsHalf, int tid)
{
  int rl0 = tid >> 3;
  int cb  = (tid & 7) * 16;
  int w   = tid >> 6;
  #pragma unroll
  for (int j = 0; j < 2; j++){
    int rl  = j*64 + rl0;
    int scb = cb ^ ((rl & 7) << 4);
    const unsigned short* src = gsrc + (size_t)rl*ldElems + (scb >> 1);
    __builtin_amdgcn_global_load_lds(
        (const __attribute__((address_space(1))) void*)src,
        (__attribute__((address_space(3))) void*)(ldsHalf + j*4096 + w*512),
        16, 0, 0);
  }
}

__device__ __forceinline__ void read_b4(const unsigned short* Bb,
                                        short8v (&b)[4][2], int wn, int fr, int colOff)
{
  #pragma unroll
  for (int n=0;n<4;n++){
    const char* rb = (const char*)Bb + (size_t)((wn*64 + n*16 + fr)*128);
    b[n][0] = *(const short8v*)(rb + colOff);
    b[n][1] = *(const short8v*)(rb + (colOff ^ 64));
  }
}

template<int P>
__device__ __forceinline__ void subphase(const unsigned short* Ab, int wm, int fr, int colOff,
                                         const short8v (&b)[4][2], f32x4 (&acc)[8][4])
{
  short8v a[2][2];
  #pragma unroll
  for (int i=0;i<2;i++){
    const char* rb = (const char*)Ab + (size_t)((wm*128 + (P*2+i)*16 + fr)*128);
    a[i][0] = *(const short8v*)(rb + colOff);
    a[i][1] = *(const short8v*)(rb + (colOff ^ 64));
  }
  __builtin_amdgcn_s_setprio(1);
  #pragma unroll
  for (int i=0;i<2;i++){
    #pragma unroll
    for (int n=0;n<4;n++){
      acc[P*2+i][n] = __builtin_amdgcn_mfma_f32_16x16x32_bf16(a[i][0], b[n][0], acc[P*2+i][n],0,0,0);
      acc[P*2+i][n] = __builtin_amdgcn_mfma_f32_16x16x32_bf16(a[i][1], b[n][1], acc[P*2+i][n],0,0,0);
    }
  }
  __builtin_amdgcn_s_setprio(0);
}

#define WAITV(N)  asm volatile("s_waitcnt vmcnt(" #N ")" ::: "memory")

// ------ GEMM1 + fused SwiGLU: act[g] = swiglu(x * gu'[g]^T) * w_tg -------------
__global__ __launch_bounds__(512, 2) void gemm1_kernel(
    const unsigned short* __restrict__ xb, const unsigned short* __restrict__ gu,
    const float* __restrict__ wtg, unsigned short* __restrict__ actb)
{
  __shared__ unsigned short Al[2][16384];
  __shared__ unsigned short Bl[2][16384];
  int tid = threadIdx.x, lane = tid & 63, w = tid >> 6;
  int wm = w >> 2, wn = w & 3;
  int fr = lane & 15;
  int colOff = ((lane >> 4) * 16) ^ ((fr & 7) << 4);
  // XCD panel grouping: members of a (n0,g) panel share id%8 -> same XCD L2
  int bid = blockIdx.x;
  int P = bid % 48, mb = bid / 48;
  int m0 = mb * 256, n0 = (P % 6) * 256, g = P / 6;
  const unsigned short* Abase = xb + (size_t)m0 * HDIM;
  const unsigned short* Bbase = gu + ((size_t)g * 1536 + n0) * HDIM;

  f32x4 acc[8][4];
  #pragma unroll
  for (int m=0;m<8;m++){
    #pragma unroll
    for (int n=0;n<4;n++) acc[m][n] = (f32x4){0,0,0,0};
  }
  short8v b[4][2];

  #define STG1(buf, kt2) do { \
    stage_half_g(Bbase + (size_t)(kt2)*64,                    HDIM, &Bl[buf][0],    tid); \
    stage_half_g(Bbase + (size_t)128*HDIM + (size_t)(kt2)*64, HDIM, &Bl[buf][8192], tid); \
    stage_half_g(Abase + (size_t)(kt2)*64,                    HDIM, &Al[buf][0],    tid); \
    stage_half_g(Abase + (size_t)128*HDIM + (size_t)(kt2)*64, HDIM, &Al[buf][8192], tid); \
  } while(0)

  STG1(0, 0);
  WAITV(0);
  __builtin_amdgcn_s_barrier();

  for (int kt = 0; kt < 31; ++kt){
    int cur = kt & 1, nb = cur ^ 1;
    STG1(nb, kt+1);
    __builtin_amdgcn_sched_barrier(0);
    read_b4(Bl[cur], b, wn, fr, colOff);
    subphase<0>(Al[cur], wm, fr, colOff, b, acc);
    subphase<1>(Al[cur], wm, fr, colOff, b, acc);
    subphase<2>(Al[cur], wm, fr, colOff, b, acc);
    subphase<3>(Al[cur], wm, fr, colOff, b, acc);
    WAITV(0);
    __builtin_amdgcn_s_barrier();
  }
  read_b4(Bl[1], b, wn, fr, colOff);
  subphase<0>(Al[1], wm, fr, colOff, b, acc);
  subphase<1>(Al[1], wm, fr, colOff, b, acc);
  subphase<2>(Al[1], wm, fr, colOff, b, acc);
  subphase<3>(Al[1], wm, fr, colOff, b, acc);
  #undef STG1

  // fused SwiGLU epilogue: acc[mi][2q]=gate, acc[mi][2q+1]=up for i = qcol*16+fr
  int r0 = (lane >> 4) * 4;
  int qbase = (n0 + wn * 64) >> 5;
  #pragma unroll
  for (int mi = 0; mi < 8; mi++){
    int trow = m0 + wm*128 + mi*16 + r0;
    #pragma unroll
    for (int q = 0; q < 2; q++){
      int icol = (qbase + q)*16 + fr;
      #pragma unroll
      for (int j = 0; j < 4; j++){
        int t = trow + j;
        float wv = wtg[(size_t)t*NGRP + g];
        float gf = acc[mi][2*q][j];
        float uf = acc[mi][2*q+1][j];
        float sg = gf / (1.f + expf(-gf));
        actb[((size_t)g*T_TOK + t)*IDIM + icol] = f2b(sg * uf * wv);
      }
    }
  }
}

// ------ GEMM2 split-K (z=4, 2 groups each): f32 partials -----------------------
__global__ __launch_bounds__(512, 2) void gemm2_kernel(
    const unsigned short* __restrict__ actb, const unsigned short* __restrict__ dnb,
    float* __restrict__ part)
{
  __shared__ unsigned short Al[2][16384];
  __shared__ unsigned short Bl[2][16384];
  int tid = threadIdx.x, lane = tid & 63, w = tid >> 6;
  int wm = w >> 2, wn = w & 3;
  int fr = lane & 15;
  int colOff = ((lane >> 4) * 16) ^ ((fr & 7) << 4);
  int bid = blockIdx.x;
  int P = bid % 32, mb = bid / 32;
  int m0 = mb * 256, n0 = (P % 8) * 256, z = P / 8;

  f32x4 acc[8][4];
  #pragma unroll
  for (int m=0;m<8;m++){
    #pragma unroll
    for (int n=0;n<4;n++) acc[m][n] = (f32x4){0,0,0,0};
  }
  short8v b[4][2];

  #define STG2(buf, kt2) do { \
    int gi = ((kt2) >= 12) ? 1 : 0; \
    int gg = z*2 + gi; \
    int kk = ((kt2) - gi*12) * 64; \
    const unsigned short* Aseg = actb + (size_t)(gg*T_TOK + m0)*IDIM + kk; \
    const unsigned short* Bseg = dnb  + (size_t)(gg*HDIM + n0)*IDIM + kk; \
    stage_half_g(Bseg,                    IDIM, &Bl[buf][0],    tid); \
    stage_half_g(Bseg + (size_t)128*IDIM, IDIM, &Bl[buf][8192], tid); \
    stage_half_g(Aseg,                    IDIM, &Al[buf][0],    tid); \
    stage_half_g(Aseg + (size_t)128*IDIM, IDIM, &Al[buf][8192], tid); \
  } while(0)

  STG2(0, 0);
  WAITV(0);
  __builtin_amdgcn_s_barrier();

  for (int kt = 0; kt < 23; ++kt){
    int cur = kt & 1, nb = cur ^ 1;
    STG2(nb, kt+1);
    __builtin_amdgcn_sched_barrier(0);
    read_b4(Bl[cur], b, wn, fr, colOff);
    subphase<0>(Al[cur], wm, fr, colOff, b, acc);
    subphase<1>(Al[cur], wm, fr, colOff, b, acc);
    subphase<2>(Al[cur], wm, fr, colOff, b, acc);
    subphase<3>(Al[cur], wm, fr, colOff, b, acc);
    WAITV(0);
    __builtin_amdgcn_s_barrier();
  }
  read_b4(Bl[1], b, wn, fr, colOff);
  subphase<0>(Al[1], wm, fr, colOff, b, acc);
  subphase<1>(Al[1], wm, fr, colOff, b, acc);
  subphase<2>(Al[1], wm, fr, colOff, b, acc);
  subphase<3>(Al[1], wm, fr, colOff, b, acc);
  #undef STG2

  float* Cb = part + (size_t)z * T_TOK * HDIM;
  int r0 = (lane >> 4) * 4;
  #pragma unroll
  for (int mi = 0; mi < 8; mi++){
    int row = m0 + wm*128 + mi*16 + r0;
    #pragma unroll
    for (int n = 0; n < 4; n++){
      int cc = n0 + wn*64 + n*16 + fr;
      #pragma unroll
      for (int j = 0; j < 4; j++){
        Cb[(size_t)(row + j)*HDIM + cc] = acc[mi][n][j];
      }
    }
  }
}

// ---------------- Final reduce over 4 partials ---------------------------------
__global__ __launch_bounds__(256) void reduce_kernel(
    const float* __restrict__ p, float* __restrict__ o)
{
  size_t i = ((size_t)blockIdx.x*256 + threadIdx.x)*4;
  float4 a0 = *(const float4*)(p + i);
  float4 a1 = *(const float4*)(p + 4194304 + i);
  float4 a2 = *(const float4*)(p + 8388608 + i);
  float4 a3 = *(const float4*)(p + 12582912 + i);
  float4 r;
  r.x = a0.x + a1.x + a2.x + a3.x;
  r.y = a0.y + a1.y + a2.y + a3.y;
  r.z = a0.z + a1.z + a2.z + a3.z;
  r.w = a0.w + a1.w + a2.w + a3.w;
  *(float4*)(o + i) = r;
}

extern "C" void kernel_launch(void* const* d_in, const int* in_sizes, int n_in,
                              void* d_out, int out_size, void* d_ws, size_t ws_size,
                              hipStream_t stream)
{
  (void)in_sizes; (void)n_in; (void)out_size; (void)ws_size;
  const float* x   = (const float*)d_in[0];
  const float* gw  = (const float*)d_in[1];
  const float* gup = (const float*)d_in[2];
  const float* dnp = (const float*)d_in[3];
  const int*   mg  = (const int*)d_in[4];
  const int*   de  = (const int*)d_in[5];
  float* out = (float*)d_out;
  char* ws = (char*)d_ws;

  // layout: [wtg 64K][xb 8M][dnb 24M][actb 24M][part 64M]; gub aliases part
  float*          wtg  = (float*)(ws + 0);
  unsigned short* xb   = (unsigned short*)(ws + 65536);
  unsigned short* dnb  = (unsigned short*)(ws + 8454144);
  unsigned short* actb = (unsigned short*)(ws + 33619968);
  float*          part = (float*)(ws + 58785792);            // 64 MiB
  unsigned short* gub  = (unsigned short*)(ws + 58785792);   // 48 MiB, dead before gemm2

  router_kernel<<<512, 256, 0, stream>>>(x, gw, mg, wtg, xb);
  convert_gu_kernel<<<dim3(3072,1,8), 256, 0, stream>>>(gup, gub, de);
  convert_dn_kernel<<<dim3(1536,1,8), 256, 0, stream>>>(dnp, dnb, de);
  gemm1_kernel<<<384, 512, 0, stream>>>(xb, gub, wtg, actb);
  gemm2_kernel<<<256, 512, 0, stream>>>(actb, dnb, part);
  reduce_kernel<<<4096, 256, 0, stream>>>(part, out);
}

// Round 5
// 239.627 us; speedup vs baseline: 1.2015x; 1.0920x over previous
//
#include <hip/hip_runtime.h>
#include <hip/hip_bf16.h>

typedef __attribute__((ext_vector_type(8))) short short8v;
typedef __attribute__((ext_vector_type(4))) float f32x4;

#define T_TOK 2048
#define HDIM  2048
#define IDIM  768
#define NGRP  8

__device__ __forceinline__ unsigned short f2b(float f){
  unsigned u = __float_as_uint(f);
  u = u + 0x7FFFu + ((u >> 16) & 1u);
  return (unsigned short)(u >> 16);
}
__device__ __forceinline__ float b2f(unsigned short s){
  return __uint_as_float(((unsigned)s) << 16);
}

// ---------------- Router: logits -> softmax -> top8 -> w_tg; also x -> bf16 ----
__global__ __launch_bounds__(256) void router_kernel(
    const float* __restrict__ x, const float* __restrict__ gw,
    const int* __restrict__ mg, float* __restrict__ wtg,
    unsigned short* __restrict__ xb)
{
  __shared__ float xs[4][2048];
  __shared__ float lg[4][32];
  int tid = threadIdx.x;
  int t0 = blockIdx.x * 4;

  #pragma unroll
  for (int k = 0; k < 8; k++){
    int idx = k*256 + tid;
    int tok = idx >> 9, wi = idx & 511;
    float4 v = ((const float4*)(x + (size_t)(t0 + tok)*HDIM))[wi];
    ((float4*)xs[tok])[wi] = v;
    ushort4 b; b.x=f2b(v.x); b.y=f2b(v.y); b.z=f2b(v.z); b.w=f2b(v.w);
    ((ushort4*)(xb + (size_t)(t0+tok)*HDIM))[wi] = b;
  }
  __syncthreads();

  int e = tid >> 3, ch = tid & 7;
  float s0=0.f, s1=0.f, s2=0.f, s3=0.f;
  const float4* gv = (const float4*)(gw + (size_t)e*HDIM);
  #pragma unroll 4
  for (int k = 0; k < 64; k++){
    int i4 = ch + 8*k;
    float4 b  = gv[i4];
    float4 a0 = ((const float4*)xs[0])[i4];
    float4 a1 = ((const float4*)xs[1])[i4];
    float4 a2 = ((const float4*)xs[2])[i4];
    float4 a3 = ((const float4*)xs[3])[i4];
    s0 += a0.x*b.x + a0.y*b.y + a0.z*b.z + a0.w*b.w;
    s1 += a1.x*b.x + a1.y*b.y + a1.z*b.z + a1.w*b.w;
    s2 += a2.x*b.x + a2.y*b.y + a2.z*b.z + a2.w*b.w;
    s3 += a3.x*b.x + a3.y*b.y + a3.z*b.z + a3.w*b.w;
  }
  #pragma unroll
  for (int off=1; off<8; off<<=1){
    s0 += __shfl_xor(s0, off); s1 += __shfl_xor(s1, off);
    s2 += __shfl_xor(s2, off); s3 += __shfl_xor(s3, off);
  }
  if (ch == 0){ lg[0][e]=s0; lg[1][e]=s1; lg[2][e]=s2; lg[3][e]=s3; }
  __syncthreads();

  int wv = tid >> 6, lane = tid & 63;
  float val = (lane < 32) ? lg[wv][lane] : -1e30f;
  float mx = val;
  #pragma unroll
  for (int off=16; off; off>>=1) mx = fmaxf(mx, __shfl_xor(mx, off));
  float p = (lane < 32) ? expf(val - mx) : 0.f;
  float sm = p;
  #pragma unroll
  for (int off=16; off; off>>=1) sm += __shfl_xor(sm, off);
  float v = (lane < 32) ? (p / sm) : -1.f;
  int idx = lane;
  float vals[8]; int idxs[8];
  #pragma unroll
  for (int it=0; it<8; it++){
    float bv = v; int bi = idx;
    #pragma unroll
    for (int off=32; off; off>>=1){
      float ov = __shfl_xor(bv, off); int oi = __shfl_xor(bi, off);
      if (ov > bv || (ov == bv && oi < bi)){ bv = ov; bi = oi; }
    }
    vals[it] = bv; idxs[it] = bi;
    if (lane == bi) v = -1.f;
  }
  float tot = vals[0]+vals[1]+vals[2]+vals[3]+vals[4]+vals[5]+vals[6]+vals[7];
  float racc = 0.f;
  #pragma unroll
  for (int it=0; it<8; it++){
    int grp = mg[idxs[it]];
    if (lane == grp) racc += vals[it] / tot;
  }
  if (lane < 8) wtg[(size_t)(t0+wv)*NGRP + lane] = racc;
}

// ------- Convert gate_up with gate/up 16-col interleave (for fused swiglu) -----
__global__ __launch_bounds__(256) void convert_gu_kernel(
    const float* __restrict__ src, unsigned short* __restrict__ dst,
    const int* __restrict__ de)
{
  int g = blockIdx.z;
  int i4 = blockIdx.x*256 + threadIdx.x;
  int j  = i4 >> 9;
  int c4 = i4 & 511;
  int q = j >> 5, r = j & 31;
  int srow = (r < 16) ? (q*16 + r) : (768 + q*16 + (r - 16));
  const float4* s = (const float4*)(src + ((size_t)de[g]*1536 + srow)*HDIM);
  float4 vv = s[c4];
  ushort4 b; b.x=f2b(vv.x); b.y=f2b(vv.y); b.z=f2b(vv.z); b.w=f2b(vv.w);
  ((ushort4*)(dst + ((size_t)g*1536 + j)*HDIM))[c4] = b;
}

__global__ __launch_bounds__(256) void convert_dn_kernel(
    const float* __restrict__ src, unsigned short* __restrict__ dst,
    const int* __restrict__ de)
{
  int g = blockIdx.z;
  size_t i4 = (size_t)blockIdx.x*256 + threadIdx.x;
  const float4* s = (const float4*)(src + (size_t)de[g]*1572864);
  float4 vv = s[i4];
  ushort4 b; b.x=f2b(vv.x); b.y=f2b(vv.y); b.z=f2b(vv.z); b.w=f2b(vv.w);
  ((ushort4*)(dst + (size_t)g*1572864))[i4] = b;
}

// ============== deep-pipelined GEMM machinery: BK=32, 4-deep LDS ring ==========
// Tile [R][32] bf16, rows of 64 B, linear layout (stride-64B rows are bank-
// balanced for the b128 frag reads -- no swizzle needed).

template<int R>
__device__ __forceinline__ void stage_tile(const unsigned short* __restrict__ gsrc,
                                           int ldE, unsigned short* __restrict__ lds,
                                           int tid)
{
  #pragma unroll
  for (int j = 0; j < R/128; j++){
    int row = j*128 + (tid >> 2);
    const unsigned short* src = gsrc + (size_t)row*ldE + (tid & 3)*8;
    __builtin_amdgcn_global_load_lds(
        (const __attribute__((address_space(1))) void*)src,
        (__attribute__((address_space(3))) void*)(lds + j*4096 + (tid >> 6)*512),
        16, 0, 0);
  }
}

__device__ __forceinline__ short8v rfrag(const unsigned short* lds, int r, int s){
  return *(const short8v*)((const char*)lds + r*64 + (s << 4));
}

#define WAITV(N)  asm volatile("s_waitcnt vmcnt(" #N ")" ::: "memory")
#define TOPBAR()  do { __builtin_amdgcn_s_barrier(); __builtin_amdgcn_sched_barrier(0); } while(0)

// ------ GEMM1 + fused SwiGLU: act[g] = swiglu(x * gu'[g]^T) * w_tg -------------
// BM=256, BN=128, grid 8mb x 12nb x 8g = 768 = 3 full rounds of 256 CUs.
__global__ __launch_bounds__(512, 2) void gemm1_kernel(
    const unsigned short* __restrict__ xb, const unsigned short* __restrict__ gu,
    const float* __restrict__ wtg, unsigned short* __restrict__ actb)
{
  __shared__ unsigned short Al[4][8192];   // 4 x 16 KB
  __shared__ unsigned short Bl[4][4096];   // 4 x  8 KB
  int tid = threadIdx.x, lane = tid & 63, w = tid >> 6;
  int wm = w >> 1, wn = w & 1;             // 4M x 2N -> per-wave 64x64
  int fr = lane & 15, sl = lane >> 4;

  // XCD-chunked bijective mapping: xcd owns 2 mb-slices x 48 panels
  int bid = blockIdx.x;
  int xcd = bid & 7, j = bid >> 3;                  // j 0..95
  int panel = ((xcd & 1) ? 48 : 0) + (j >> 1);      // 0..95
  int mb = ((xcd >> 1) << 1) + (j & 1);             // 0..7
  int nb = panel % 12, g = panel / 12;
  int m0 = mb * 256, n0 = nb * 128;
  const unsigned short* Abase = xb + (size_t)m0 * HDIM;
  const unsigned short* Bbase = gu + ((size_t)g * 1536 + n0) * HDIM;

  f32x4 acc[4][4];
  #pragma unroll
  for (int m=0;m<4;m++){
    #pragma unroll
    for (int n=0;n<4;n++) acc[m][n] = (f32x4){0,0,0,0};
  }

  #define BODY1(t, DOSTAGE) do { \
    int buf = (t) & 3; \
    short8v av[4], bv[4]; \
    _Pragma("unroll") for (int m=0;m<4;m++) av[m] = rfrag(&Al[buf][0], wm*64 + m*16 + fr, sl); \
    _Pragma("unroll") for (int n=0;n<4;n++) bv[n] = rfrag(&Bl[buf][0], wn*64 + n*16 + fr, sl); \
    if (DOSTAGE){ int k2 = (t)+3, b2 = k2 & 3; \
      stage_tile<256>(Abase + k2*32, HDIM, &Al[b2][0], tid); \
      stage_tile<128>(Bbase + k2*32, HDIM, &Bl[b2][0], tid); } \
    asm volatile("s_waitcnt lgkmcnt(0)" ::: "memory"); \
    __builtin_amdgcn_sched_barrier(0); \
    __builtin_amdgcn_s_setprio(1); \
    _Pragma("unroll") for (int m=0;m<4;m++){ \
      _Pragma("unroll") for (int n=0;n<4;n++){ \
        acc[m][n] = __builtin_amdgcn_mfma_f32_16x16x32_bf16(av[m], bv[n], acc[m][n],0,0,0); } } \
    __builtin_amdgcn_s_setprio(0); \
  } while(0)

  const int NT = 64;
  stage_tile<256>(Abase,      HDIM, &Al[0][0], tid); stage_tile<128>(Bbase,      HDIM, &Bl[0][0], tid);
  stage_tile<256>(Abase + 32, HDIM, &Al[1][0], tid); stage_tile<128>(Bbase + 32, HDIM, &Bl[1][0], tid);
  stage_tile<256>(Abase + 64, HDIM, &Al[2][0], tid); stage_tile<128>(Bbase + 64, HDIM, &Bl[2][0], tid);

  for (int t = 0; t < NT-3; ++t){
    WAITV(6); TOPBAR();
    BODY1(t, 1);
  }
  WAITV(6); TOPBAR(); BODY1(NT-3, 0);
  WAITV(3); TOPBAR(); BODY1(NT-2, 0);
  WAITV(0); TOPBAR(); BODY1(NT-1, 0);
  #undef BODY1

  // fused SwiGLU epilogue: n-frags [gate,up,gate,up] by construction of gu'
  int r0 = (lane >> 4) * 4;
  int q0 = (n0 + wn*64) >> 5;
  #pragma unroll
  for (int m = 0; m < 4; m++){
    int trow = m0 + wm*64 + m*16 + r0;
    #pragma unroll
    for (int q = 0; q < 2; q++){
      int icol = (q0 + q)*16 + fr;
      #pragma unroll
      for (int jj = 0; jj < 4; jj++){
        int t = trow + jj;
        float wv = wtg[(size_t)t*NGRP + g];
        float gf = acc[m][2*q][jj];
        float uf = acc[m][2*q+1][jj];
        float sg = gf / (1.f + expf(-gf));
        actb[((size_t)g*T_TOK + t)*IDIM + icol] = f2b(sg * uf * wv);
      }
    }
  }
}

// ------ GEMM2 split-K=2 (4 groups each): f32 partials --------------------------
// BM=128, BN=256, grid 16mb x 8nb x 2z = 256 = 1 full round.
__global__ __launch_bounds__(512, 2) void gemm2_kernel(
    const unsigned short* __restrict__ actb, const unsigned short* __restrict__ dnb,
    float* __restrict__ part)
{
  __shared__ unsigned short Al[4][4096];   // 4 x  8 KB
  __shared__ unsigned short Bl[4][8192];   // 4 x 16 KB
  int tid = threadIdx.x, lane = tid & 63, w = tid >> 6;
  int wm = w >> 2, wn = w & 3;             // 2M x 4N -> per-wave 64x64
  int fr = lane & 15, sl = lane >> 4;

  int bid = blockIdx.x;
  int xcd = bid & 7, j = bid >> 3;                  // j 0..31
  int panel = ((xcd & 1) ? 8 : 0) + (j >> 2);       // 0..15
  int mb = ((xcd >> 1) << 2) + (j & 3);             // 0..15
  int nb = panel & 7, z = panel >> 3;
  int m0 = mb * 128, n0 = nb * 256;

  f32x4 acc[4][4];
  #pragma unroll
  for (int m=0;m<4;m++){
    #pragma unroll
    for (int n=0;n<4;n++) acc[m][n] = (f32x4){0,0,0,0};
  }

  // tile kt (0..95): gi = kt/24, kk = (kt%24)*32, group = z*4+gi
  #define STAGE2(kt, b2) do { \
    int gi = (kt) / 24; int kk = ((kt) - gi*24) * 32; int gg = z*4 + gi; \
    stage_tile<128>(actb + ((size_t)gg*T_TOK + m0)*IDIM + kk, IDIM, &Al[b2][0], tid); \
    stage_tile<256>(dnb  + ((size_t)gg*HDIM + n0)*IDIM + kk, IDIM, &Bl[b2][0], tid); \
  } while(0)

  #define BODY2(t, DOSTAGE) do { \
    int buf = (t) & 3; \
    short8v av[4], bv[4]; \
    _Pragma("unroll") for (int m=0;m<4;m++) av[m] = rfrag(&Al[buf][0], wm*64 + m*16 + fr, sl); \
    _Pragma("unroll") for (int n=0;n<4;n++) bv[n] = rfrag(&Bl[buf][0], wn*64 + n*16 + fr, sl); \
    if (DOSTAGE){ int k2 = (t)+3; STAGE2(k2, k2 & 3); } \
    asm volatile("s_waitcnt lgkmcnt(0)" ::: "memory"); \
    __builtin_amdgcn_sched_barrier(0); \
    __builtin_amdgcn_s_setprio(1); \
    _Pragma("unroll") for (int m=0;m<4;m++){ \
      _Pragma("unroll") for (int n=0;n<4;n++){ \
        acc[m][n] = __builtin_amdgcn_mfma_f32_16x16x32_bf16(av[m], bv[n], acc[m][n],0,0,0); } } \
    __builtin_amdgcn_s_setprio(0); \
  } while(0)

  const int NT = 96;
  STAGE2(0, 0); STAGE2(1, 1); STAGE2(2, 2);

  for (int t = 0; t < NT-3; ++t){
    WAITV(6); TOPBAR();
    BODY2(t, 1);
  }
  WAITV(6); TOPBAR(); BODY2(NT-3, 0);
  WAITV(3); TOPBAR(); BODY2(NT-2, 0);
  WAITV(0); TOPBAR(); BODY2(NT-1, 0);
  #undef BODY2
  #undef STAGE2

  float* Cb = part + (size_t)z * T_TOK * HDIM;
  int r0 = (lane >> 4) * 4;
  #pragma unroll
  for (int m = 0; m < 4; m++){
    int row = m0 + wm*64 + m*16 + r0;
    #pragma unroll
    for (int n = 0; n < 4; n++){
      int cc = n0 + wn*64 + n*16 + fr;
      #pragma unroll
      for (int jj = 0; jj < 4; jj++){
        Cb[(size_t)(row + jj)*HDIM + cc] = acc[m][n][jj];
      }
    }
  }
}

// ---------------- Final reduce over 2 partials ---------------------------------
__global__ __launch_bounds__(256) void reduce_kernel(
    const float* __restrict__ p, float* __restrict__ o)
{
  size_t i = ((size_t)blockIdx.x*256 + threadIdx.x)*4;
  float4 a0 = *(const float4*)(p + i);
  float4 a1 = *(const float4*)(p + 4194304 + i);
  float4 r;
  r.x = a0.x + a1.x;
  r.y = a0.y + a1.y;
  r.z = a0.z + a1.z;
  r.w = a0.w + a1.w;
  *(float4*)(o + i) = r;
}

extern "C" void kernel_launch(void* const* d_in, const int* in_sizes, int n_in,
                              void* d_out, int out_size, void* d_ws, size_t ws_size,
                              hipStream_t stream)
{
  (void)in_sizes; (void)n_in; (void)out_size; (void)ws_size;
  const float* x   = (const float*)d_in[0];
  const float* gw  = (const float*)d_in[1];
  const float* gup = (const float*)d_in[2];
  const float* dnp = (const float*)d_in[3];
  const int*   mg  = (const int*)d_in[4];
  const int*   de  = (const int*)d_in[5];
  float* out = (float*)d_out;
  char* ws = (char*)d_ws;

  // layout: [wtg 64K][xb 8M][dnb 24M][actb 24M][gub 48M | part 33.5M aliased]
  float*          wtg  = (float*)(ws + 0);
  unsigned short* xb   = (unsigned short*)(ws + 65536);
  unsigned short* dnb  = (unsigned short*)(ws + 8454144);
  unsigned short* actb = (unsigned short*)(ws + 33619968);
  unsigned short* gub  = (unsigned short*)(ws + 58785792);   // dead before gemm2
  float*          part = (float*)(ws + 58785792);

  router_kernel<<<512, 256, 0, stream>>>(x, gw, mg, wtg, xb);
  convert_gu_kernel<<<dim3(3072,1,8), 256, 0, stream>>>(gup, gub, de);
  convert_dn_kernel<<<dim3(1536,1,8), 256, 0, stream>>>(dnp, dnb, de);
  gemm1_kernel<<<768, 512, 0, stream>>>(xb, gub, wtg, actb);
  gemm2_kernel<<<256, 512, 0, stream>>>(actb, dnb, part);
  reduce_kernel<<<4096, 256, 0, stream>>>(part, out);
}